// Round 3
// baseline (512.830 us; speedup 1.0000x reference)
//
#include <hip/hip_runtime.h>
#include <hip/hip_cooperative_groups.h>
#include <math.h>

#define B 32
#define D 512
#define H 1024
#define G4 4096      // 4*H
#define PCH 16       // plastic i-chunks (64 i's each)
#define GCH 12       // gate i-chunks of 128: 8 cover wh (1024), 4 cover wx (512)
#define NBLK 704     // 192 gate units + 512 plastic units; co-resident (<=1024 @ 4/CU)

namespace cg = cooperative_groups;

// Single fused cooperative kernel.
// Phase 1 (heterogeneous):
//   blocks [0,192):  gate partials gp[c][b][j] = sum_{i in chunk c} in[b,i]*W[i,j]
//                    unit = (c, jb, bh): thread owns 4 j (float4 W load), 8 b in regs
//   blocks [192,704): plastic partials pp[c][b][h] += h0[b,i]*alpha[i,h]*Hebb0[b,i,h]
// Phase 2: blocks [0,128): reduce partials, activations -> h1, c1, tanh_g
// Phase 3: all blocks grid-stride over (b,h) rows:
//   Hebb1[b,h,i] = clip(Hebb0[b,h,i] + eta*h0[b,h]*tanh_g[b,i], -1, 1)
__global__ __launch_bounds__(256, 4) void k_fused(
    const float* __restrict__ x, const float* __restrict__ h0,
    const float* __restrict__ c0, const float* __restrict__ hebb,
    const float* __restrict__ wh, const float* __restrict__ wx,
    const float* __restrict__ bias, const float* __restrict__ alpha,
    const float* __restrict__ eta, float* __restrict__ out,
    float* __restrict__ pp, float* __restrict__ gp, float* __restrict__ tg) {
  cg::grid_group grid = cg::this_grid();
  const int blk = blockIdx.x;
  const int tid = threadIdx.x;

  // ---------------- phase 1 ----------------
  if (blk < 192) {
    const int c  = blk >> 4;          // 0..11
    const int r  = blk & 15;
    const int jb = r & 3;             // j-quarter
    const int b0 = (r >> 2) * 8;      // batch group of 8
    const int j4 = jb * 1024 + tid * 4;
    const float* W;
    const float* in;
    int i0, ld;
    if (c < 8) { W = wh; in = h0; i0 = c * 128;       ld = H; }
    else       { W = wx; in = x;  i0 = (c - 8) * 128; ld = D; }
    float4 acc[8];
#pragma unroll
    for (int bb = 0; bb < 8; ++bb) acc[bb] = make_float4(0.f, 0.f, 0.f, 0.f);
#pragma unroll 2
    for (int i = i0; i < i0 + 128; ++i) {
      float4 w = *(const float4*)(W + (size_t)i * G4 + j4);
#pragma unroll
      for (int bb = 0; bb < 8; ++bb) {
        float hv = in[(b0 + bb) * ld + i];   // wave-uniform -> s_load
        acc[bb].x += hv * w.x;
        acc[bb].y += hv * w.y;
        acc[bb].z += hv * w.z;
        acc[bb].w += hv * w.w;
      }
    }
#pragma unroll
    for (int bb = 0; bb < 8; ++bb)
      *(float4*)(gp + ((size_t)c * B + b0 + bb) * G4 + j4) = acc[bb];
  } else {
    const int u = blk - 192;          // 0..511
    const int b = u >> 4;
    const int c = u & 15;
    const int h4 = tid * 4;
    const int i0 = c * 64;
    const float* hb = hebb + (size_t)b * H * H;
    float4 acc = make_float4(0.f, 0.f, 0.f, 0.f);
#pragma unroll 4
    for (int i = i0; i < i0 + 64; ++i) {
      float hv = h0[b * H + i];             // wave-uniform -> s_load
      float4 a = *(const float4*)(alpha + (size_t)i * H + h4);
      float4 e = *(const float4*)(hb + (size_t)i * H + h4);
      acc.x += hv * a.x * e.x;
      acc.y += hv * a.y * e.y;
      acc.z += hv * a.z * e.z;
      acc.w += hv * a.w * e.w;
    }
    *(float4*)(pp + ((size_t)c * B + b) * H + h4) = acc;
  }

  grid.sync();

  // ---------------- phase 2 ----------------
  if (blk < 128) {
    const int t = blk * 256 + tid;    // 0..B*H-1
    const int b = t >> 10;
    const int h = t & (H - 1);
    float sf = bias[h], si = bias[H + h], so = bias[2 * H + h], sg = bias[3 * H + h];
#pragma unroll
    for (int c = 0; c < GCH; ++c) {
      const float* g = gp + ((size_t)c * B + b) * G4;
      sf += g[h];
      si += g[H + h];
      so += g[2 * H + h];
      sg += g[3 * H + h];
    }
#pragma unroll
    for (int c = 0; c < PCH; ++c) sg += pp[((size_t)c * B + b) * H + h];
    float fg = 1.f / (1.f + expf(-sf));
    float ig = 1.f / (1.f + expf(-si));
    float og = 1.f / (1.f + expf(-so));
    float tgv = tanhf(sg);
    float c1 = fg * c0[t] + ig * tgv;
    float h1 = og * tanhf(c1);
    out[t] = h1;
    out[B * H + t] = c1;
    tg[t] = tgv;
  }

  grid.sync();

  // ---------------- phase 3 ----------------
  {
    const float e = eta[0];
    const int t4 = tid * 4;
    float* out3 = out + 2 * B * H;
#pragma unroll 2
    for (int row = blk; row < B * H; row += NBLK) {
      const int b = row >> 10;
      const float s = e * h0[row];
      float4 tv = *(const float4*)(tg + b * H + t4);
      float4 v = *(const float4*)(hebb + (size_t)row * H + t4);
      float4 rr;
      rr.x = fminf(fmaxf(v.x + s * tv.x, -1.f), 1.f);
      rr.y = fminf(fmaxf(v.y + s * tv.y, -1.f), 1.f);
      rr.z = fminf(fmaxf(v.z + s * tv.z, -1.f), 1.f);
      rr.w = fminf(fmaxf(v.w + s * tv.w, -1.f), 1.f);
      *(float4*)(out3 + (size_t)row * H + t4) = rr;
    }
  }
}

extern "C" void kernel_launch(void* const* d_in, const int* in_sizes, int n_in,
                              void* d_out, int out_size, void* d_ws, size_t ws_size,
                              hipStream_t stream) {
  const float* x     = (const float*)d_in[0];
  const float* h0    = (const float*)d_in[1];
  const float* c0    = (const float*)d_in[2];
  const float* hebb  = (const float*)d_in[3];
  const float* wh    = (const float*)d_in[4];
  const float* wx    = (const float*)d_in[5];
  const float* bias  = (const float*)d_in[6];
  const float* alpha = (const float*)d_in[7];
  const float* eta   = (const float*)d_in[8];
  float* out = (float*)d_out;
  float* ws  = (float*)d_ws;

  float* pp = ws;                          // [PCH][B][H]   =   512 K floats (2 MB)
  float* gp = pp + (size_t)PCH * B * H;    // [GCH][B][4H]  = 1.5 M floats (6 MB)
  float* tg = gp + (size_t)GCH * B * G4;   // [B][H]        =  32 K floats

  void* args[] = {(void*)&x, (void*)&h0, (void*)&c0, (void*)&hebb,
                  (void*)&wh, (void*)&wx, (void*)&bias, (void*)&alpha,
                  (void*)&eta, (void*)&out, (void*)&pp, (void*)&gp, (void*)&tg};
  hipLaunchCooperativeKernel((void*)k_fused, dim3(NBLK), dim3(256), args, 0, stream);
}